// Round 9
// baseline (183.194 us; speedup 1.0000x reference)
//
#include <hip/hip_runtime.h>
#include <math.h>

// VQ-VAE vector quantizer for MI355X.
// z: [32, 64, 64, 64] fp32 (B, C=D, H, W), embedding: [1024, 64] fp32.
// Outputs (concatenated fp32 in d_out):
//   [0 .. 8388607]  quantized, layout (b, c, h, w)
//   [8388608]       loss = L + 0.25*L, L = mean((q - z)^2)
//   [8388609]       perplexity
//   [8388610 .. ]   encoding indices (as float), 131072 of them
//
// Round 9 (on round 8's MFMA-filter + exact-rescore, which passed exact):
//  - 128 rows/block (1024 blocks): halves redundant eh_p L2 traffic,
//    doubles compute per B-load (16 MFMA / 64B-lane-load).
//  - hi-only MFMA (drop zl term): e-rounding already dominates the bound;
//    window widened 1e-5 -> 2e-5 * sum|z| (worst-case margin 2.6x).
//    Sweeps 1 and 2 remain bit-identical arithmetic.
//  - depth-2 B prefetch (3 rotated buffers, fully unrolled static indices)
//    to cover ~207cyc L2 latency (per-tile compute ~150cyc).
//  - thresholds hoisted to registers for sweep 2; float4 rescore loads
//    (sequential ascending-d FMA order preserved -> reference-bit-exact).

#define NROWS 131072
#define KCODES 1024
#define DDIM 64
#define CAP 16

typedef __attribute__((ext_vector_type(8))) short short8v;  // 8 bf16
typedef __attribute__((ext_vector_type(4))) float f32x4;

// Prevent fp contraction (hipcc defaults to -ffp-contract=fast).
__device__ __forceinline__ float nofuse(float x) {
    asm("" : "+v"(x));
    return x;
}

// numpy pairwise_sum for n=64 of terms a[i]*a[i] (8-stripe + fixed tree).
template <typename F>
__device__ __forceinline__ float pairwise64_sq(F load) {
    float r[8];
#pragma unroll
    for (int j = 0; j < 8; j++) {
        float v = load(j);
        r[j] = nofuse(v * v);
    }
#pragma unroll
    for (int i = 8; i < 64; i += 8) {
#pragma unroll
        for (int j = 0; j < 8; j++) {
            float v = load(i + j);
            r[j] = r[j] + nofuse(v * v);
        }
    }
    return ((r[0] + r[1]) + (r[2] + r[3])) + ((r[4] + r[5]) + (r[6] + r[7]));
}

__device__ __forceinline__ unsigned short bf16_rne(float x) {
    unsigned u = __float_as_uint(x);
    u += 0x7FFFu + ((u >> 16) & 1u);
    return (unsigned short)(u >> 16);
}

// --- kernel E: ee[k] (numpy-pairwise exact) + eh bf16 pack ---
__global__ __launch_bounds__(256) void kE(const float* __restrict__ emb,
                                          float* __restrict__ ee,
                                          unsigned short* __restrict__ eh_p) {
    int k = blockIdx.x * 256 + threadIdx.x;
    if (k >= KCODES) return;
    const float* er = emb + (size_t)k * DDIM;
    ee[k] = pairwise64_sq([&](int i) { return er[i]; });
#pragma unroll
    for (int i = 0; i < DDIM; i++) eh_p[(size_t)k * DDIM + i] = bf16_rne(er[i]);
}

#define MFMA_BF16(acc, a, b) \
    acc = __builtin_amdgcn_mfma_f32_16x16x32_bf16(a, b, acc, 0, 0, 0)

// 16 MFMAs (8 row-tiles x K=64, hi-only) for one 16-code tile, then ACT.
// Identical arithmetic in both sweeps -> bit-identical s~ values.
#define DOT_TILE(ti, B0, B1, ACT)                                       \
    {                                                                   \
        const int codeL = code0 + (ti) * 16 + (l & 15);                 \
        const float eev = ee_s[codeL];                                  \
        _Pragma("unroll") for (int rt = 0; rt < 8; rt++) {              \
            f32x4 acc = {0.f, 0.f, 0.f, 0.f};                           \
            MFMA_BF16(acc, ah[rt][0], B0);                              \
            MFMA_BF16(acc, ah[rt][1], B1);                              \
            _Pragma("unroll") for (int r = 0; r < 4; r++) {             \
                float sv = fmaf(-2.0f, acc[r], eev);                    \
                ACT(rt, r, sv, codeL);                                  \
            }                                                           \
        }                                                               \
    }

#define ACT_MIN(rt, r, sv, code) rm[rt][r] = fminf(rm[rt][r], sv);
#define ACT_COLLECT(rt, r, sv, code)                                    \
    if (sv <= thr_r[rt][r]) {                                           \
        int row_ = rt * 16 + ((l >> 4) << 2) + r;                       \
        int pos_ = atomicAdd(&cnt_s[row_], 1);                          \
        if (pos_ < CAP) cand_s[row_][pos_] = (unsigned short)(code);    \
    }

#define PRE_B(ti)                                                       \
    {                                                                   \
        const unsigned short* p_ =                                      \
            ebase + (size_t)((ti) * 16 + (l & 15)) * 64 + kg;           \
        pb0[(ti) % 3] = *(const short8v*)p_;                            \
        pb1[(ti) % 3] = *(const short8v*)(p_ + 32);                     \
    }

// --- kernel A2: MFMA filter + exact rescore + fused outputs ---
// Block: 256 threads (4 waves), 128 rows = (b, h0, h0+1). Wave wv owns
// codes [wv*256, wv*256+256) for ALL 128 rows (8 row-tile A-frags, hi-only).
// MFMA 16x16x32 bf16: A[m][k]: m=lane&15, k=(lane>>4)*8+i; B[k][n]:
// n=lane&15, same k; D[m][n]: n=lane&15, m=(lane>>4)*4+reg (m89-verified).
__global__ __launch_bounds__(256) void kA2(const float* __restrict__ z,
                                           const float* __restrict__ emb,
                                           const float* __restrict__ ee,
                                           const unsigned short* __restrict__ eh_p,
                                           int* __restrict__ counts,
                                           float* __restrict__ out_idx,
                                           float* __restrict__ out_q,
                                           double* __restrict__ loss_sum) {
    __shared__ float zt[128][65];      // [row][d]
    __shared__ float ee_s[KCODES];     // exact ee bit-copy
    __shared__ float zz_s[128];
    __shared__ float wq_s[128];        // per-row window W_row
    __shared__ float rmw_s[4][128];    // per-wave per-row mins
    __shared__ float thr_s[128];       // final per-row threshold
    __shared__ int cnt_s[128];
    __shared__ unsigned short cand_s[128][CAP];
    __shared__ int idx_s[128];
    __shared__ double wred[4];

    const int tid = threadIdx.x;
    const int blk = blockIdx.x;        // 0..1023
    const int n0 = blk * 128;
    const int b = blk >> 5;
    const int h0 = (blk & 31) * 2;

    // stage z tile: rows j=0..127 = (h0,h0+1) x w, contiguous in memory
    const float* zb = z + (size_t)b * 262144 + (size_t)h0 * 64;
    for (int i = tid; i < 128 * 64; i += 256) {
        int d = i >> 7, j = i & 127;
        zt[j][d] = zb[(size_t)d * 4096 + j];
    }
    for (int i = tid; i < KCODES; i += 256) ee_s[i] = ee[i];
    __syncthreads();

    if (tid < 128) {
        const int w = tid;
        zz_s[w] = pairwise64_sq([&](int i) { return zt[w][i]; });
        float s = 0.0f;
#pragma unroll
        for (int i = 0; i < 64; i++) s += fabsf(zt[w][i]);
        wq_s[w] = fmaf(2e-5f, s, 1e-4f);  // hi-only bound x2.6 margin
        cnt_s[w] = 0;
    }
    __syncthreads();

    const int wv = tid >> 6;           // wave id -> code range
    const int l = tid & 63;            // lane
    const int kg = (l >> 4) * 8;       // k-slice base within 32-wide half
    const int code0 = wv * 256;

    // A fragments (hi bf16 only) for ALL 128 rows = 8 row-tiles
    short8v ah[8][2];
#pragma unroll
    for (int rt = 0; rt < 8; rt++) {
        const int arow = rt * 16 + (l & 15);
#pragma unroll
        for (int kt = 0; kt < 2; kt++) {
#pragma unroll
            for (int i = 0; i < 8; i++)
                ah[rt][kt][i] = (short)bf16_rne(zt[arow][kt * 32 + kg + i]);
        }
    }

    const unsigned short* ebase = eh_p + (size_t)code0 * 64;

    // ---- sweep 1: per-row approx min over this wave's 256 codes ----
    float rm[8][4];
#pragma unroll
    for (int rt = 0; rt < 8; rt++)
#pragma unroll
        for (int r = 0; r < 4; r++) rm[rt][r] = INFINITY;
    {
        short8v pb0[3], pb1[3];
        PRE_B(0)
        PRE_B(1)
#pragma unroll
        for (int ti = 0; ti < 16; ti++) {
            if (ti + 2 < 16) PRE_B(ti + 2)
            DOT_TILE(ti, pb0[ti % 3], pb1[ti % 3], ACT_MIN)
        }
    }
    // reduce min across the 16 lanes (codes) in each lane group
#pragma unroll
    for (int rt = 0; rt < 8; rt++)
#pragma unroll
        for (int r = 0; r < 4; r++) {
            float v = rm[rt][r];
            v = fminf(v, __shfl_xor(v, 1, 64));
            v = fminf(v, __shfl_xor(v, 2, 64));
            v = fminf(v, __shfl_xor(v, 4, 64));
            v = fminf(v, __shfl_xor(v, 8, 64));
            rm[rt][r] = v;
        }
    if ((l & 15) == 0) {
#pragma unroll
        for (int rt = 0; rt < 8; rt++)
#pragma unroll
            for (int r = 0; r < 4; r++)
                rmw_s[wv][rt * 16 + ((l >> 4) << 2) + r] = rm[rt][r];
    }
    __syncthreads();
    if (tid < 128) {
        float m01 = fminf(rmw_s[0][tid], rmw_s[1][tid]);
        float m23 = fminf(rmw_s[2][tid], rmw_s[3][tid]);
        thr_s[tid] = fminf(m01, m23) + wq_s[tid];
    }
    __syncthreads();

    // hoist thresholds for this lane's 32 (rt,r) rows into registers
    float thr_r[8][4];
#pragma unroll
    for (int rt = 0; rt < 8; rt++)
#pragma unroll
        for (int r = 0; r < 4; r++)
            thr_r[rt][r] = thr_s[rt * 16 + ((l >> 4) << 2) + r];

    // ---- sweep 2: identical arithmetic, collect window candidates ----
    {
        short8v pb0[3], pb1[3];
        PRE_B(0)
        PRE_B(1)
#pragma unroll
        for (int ti = 0; ti < 16; ti++) {
            if (ti + 2 < 16) PRE_B(ti + 2)
            DOT_TILE(ti, pb0[ti % 3], pb1[ti % 3], ACT_COLLECT)
        }
    }
    __syncthreads();

    // ---- exact rescore (reference-bit-exact chain), one thread per row ----
    if (tid < 128) {
        const int w = tid;
        const float zzv = zz_s[w];
        float bv = INFINITY;
        int bi = 0;
        const int nc = cnt_s[w];
        if (nc > CAP) {
            for (int k = 0; k < KCODES; k++) {
                const float4* er = (const float4*)(emb + (size_t)k * 64);
                float dot = 0.0f;
#pragma unroll
                for (int q = 0; q < 16; q++) {
                    float4 e4 = er[q];
                    dot = __builtin_fmaf(zt[w][4 * q + 0], e4.x, dot);
                    dot = __builtin_fmaf(zt[w][4 * q + 1], e4.y, dot);
                    dot = __builtin_fmaf(zt[w][4 * q + 2], e4.z, dot);
                    dot = __builtin_fmaf(zt[w][4 * q + 3], e4.w, dot);
                }
                float tt = zzv + ee_s[k];
                float dv = tt - 2.0f * dot;
                if (dv < bv || (dv == bv && k < bi)) { bv = dv; bi = k; }
            }
        } else {
            for (int j = 0; j < nc; j++) {
                const int k = cand_s[w][j];
                const float4* er = (const float4*)(emb + (size_t)k * 64);
                float dot = 0.0f;
#pragma unroll
                for (int q = 0; q < 16; q++) {
                    float4 e4 = er[q];
                    dot = __builtin_fmaf(zt[w][4 * q + 0], e4.x, dot);
                    dot = __builtin_fmaf(zt[w][4 * q + 1], e4.y, dot);
                    dot = __builtin_fmaf(zt[w][4 * q + 2], e4.z, dot);
                    dot = __builtin_fmaf(zt[w][4 * q + 3], e4.w, dot);
                }
                float tt = zzv + ee_s[k];
                float dv = tt - 2.0f * dot;
                if (dv < bv || (dv == bv && k < bi)) { bv = dv; bi = k; }
            }
        }
        idx_s[w] = bi;
        out_idx[n0 + w] = (float)bi;
        atomicAdd(&counts[bi], 1);
    }
    __syncthreads();

    // ---- fused output: quantized gather/store + fp64 loss ----
    float* qb = out_q + (size_t)b * 262144 + (size_t)h0 * 64;
    double dsum = 0.0;
    for (int i = tid; i < 128 * 64; i += 256) {
        int c = i >> 7, j = i & 127;
        float q = emb[(size_t)idx_s[j] * 64 + c];
        float zv = zt[j][c];
        qb[(size_t)c * 4096 + j] = q;
        float df = q - zv;
        float s = df * df;
        dsum += (double)s;
    }
    for (int off = 32; off > 0; off >>= 1) dsum += __shfl_down(dsum, off, 64);
    if ((tid & 63) == 0) wred[tid >> 6] = dsum;
    __syncthreads();
    if (tid == 0) {
        double tot = (wred[0] + wred[1]) + (wred[2] + wred[3]);
        atomicAdd(loss_sum, tot);
    }
}

// --- kernel C: loss + perplexity scalars ---
__global__ __launch_bounds__(1024) void kC(const int* __restrict__ counts,
                                           const double* __restrict__ loss_sum,
                                           float* __restrict__ out_loss,
                                           float* __restrict__ out_perp) {
    __shared__ float wr[16];
    const int tid = threadIdx.x;
    float p = (float)counts[tid] * (1.0f / 131072.0f);
    float v = p + 1e-10f;
    float term = p * logf(v);
    float s = term;
    for (int off = 32; off > 0; off >>= 1) s += __shfl_down(s, off, 64);
    if ((tid & 63) == 0) wr[tid >> 6] = s;
    __syncthreads();
    if (tid == 0) {
        float tot = 0.0f;
#pragma unroll
        for (int j = 0; j < 16; j++) tot += wr[j];
        out_perp[0] = expf(-tot);
        double L = *loss_sum / 8388608.0;
        float Lf = (float)L;
        out_loss[0] = Lf + 0.25f * Lf;
    }
}

extern "C" void kernel_launch(void* const* d_in, const int* in_sizes, int n_in,
                              void* d_out, int out_size, void* d_ws, size_t ws_size,
                              hipStream_t stream) {
    const float* z = (const float*)d_in[0];
    const float* emb = (const float*)d_in[1];
    float* out = (float*)d_out;
    float* out_q = out;                    // 8388608
    float* out_loss = out + 8388608;       // 1
    float* out_perp = out + 8388609;       // 1
    float* out_idx = out + 8388610;        // 131072

    char* ws = (char*)d_ws;
    double* loss_sum = (double*)ws;                       // 8 B @ 0
    int* counts = (int*)(ws + 64);                        // 4 KB
    float* ee = (float*)(ws + 64 + 4096);                 // 4 KB
    unsigned short* eh_p = (unsigned short*)(ws + 64 + 8192);  // 128 KB

    hipMemsetAsync(d_ws, 0, 64 + 4096, stream);
    kE<<<4, 256, 0, stream>>>(emb, ee, eh_p);
    kA2<<<1024, 256, 0, stream>>>(z, emb, ee, eh_p, counts, out_idx, out_q,
                                  loss_sum);
    kC<<<1, 1024, 0, stream>>>(counts, loss_sum, out_loss, out_perp);
}

// Round 10
// 133.544 us; speedup vs baseline: 1.3718x; 1.3718x over previous
//
#include <hip/hip_runtime.h>
#include <math.h>

// VQ-VAE vector quantizer for MI355X.
// z: [32, 64, 64, 64] fp32 (B, C=D, H, W), embedding: [1024, 64] fp32.
// Outputs (concatenated fp32 in d_out):
//   [0 .. 8388607]  quantized, layout (b, c, h, w)
//   [8388608]       loss = L + 0.25*L, L = mean((q - z)^2)
//   [8388609]       perplexity
//   [8388610 .. ]   encoding indices (as float), 131072 of them
//
// Round 10: round-8 shape (64 rows/block, 2048 blocks, ~25KB LDS = good
// occupancy + 8 blocks/CU of work) + round-9's validated wins:
//   - hi-only MFMA filter (window 2e-5*sum|z| + 1e-4, proven exact in r9)
//   - depth-2 B prefetch (3 rotated buffers, static indices)
//   - thresholds in registers for sweep 2, float4 staging/rescore
//   - __launch_bounds__(256,4) to hold >=4 waves/SIMD
// Round 9's regression was occupancy (46.6KB LDS, 136 VGPR, 1024-block grid
// = 4 blocks/CU of work -> no cross-block overlap, 11% occupancy).

#define NROWS 131072
#define KCODES 1024
#define DDIM 64
#define CAP 16

typedef __attribute__((ext_vector_type(8))) short short8v;  // 8 bf16
typedef __attribute__((ext_vector_type(4))) float f32x4;

// Prevent fp contraction (hipcc defaults to -ffp-contract=fast).
__device__ __forceinline__ float nofuse(float x) {
    asm("" : "+v"(x));
    return x;
}

// numpy pairwise_sum for n=64 of terms a[i]*a[i] (8-stripe + fixed tree).
template <typename F>
__device__ __forceinline__ float pairwise64_sq(F load) {
    float r[8];
#pragma unroll
    for (int j = 0; j < 8; j++) {
        float v = load(j);
        r[j] = nofuse(v * v);
    }
#pragma unroll
    for (int i = 8; i < 64; i += 8) {
#pragma unroll
        for (int j = 0; j < 8; j++) {
            float v = load(i + j);
            r[j] = r[j] + nofuse(v * v);
        }
    }
    return ((r[0] + r[1]) + (r[2] + r[3])) + ((r[4] + r[5]) + (r[6] + r[7]));
}

__device__ __forceinline__ unsigned short bf16_rne(float x) {
    unsigned u = __float_as_uint(x);
    u += 0x7FFFu + ((u >> 16) & 1u);
    return (unsigned short)(u >> 16);
}

// --- kernel E: ee[k] (numpy-pairwise exact) + eh bf16 pack ---
__global__ __launch_bounds__(256) void kE(const float* __restrict__ emb,
                                          float* __restrict__ ee,
                                          unsigned short* __restrict__ eh_p) {
    int k = blockIdx.x * 256 + threadIdx.x;
    if (k >= KCODES) return;
    const float* er = emb + (size_t)k * DDIM;
    ee[k] = pairwise64_sq([&](int i) { return er[i]; });
#pragma unroll
    for (int i = 0; i < DDIM; i++) eh_p[(size_t)k * DDIM + i] = bf16_rne(er[i]);
}

#define MFMA_BF16(acc, a, b) \
    acc = __builtin_amdgcn_mfma_f32_16x16x32_bf16(a, b, acc, 0, 0, 0)

// 8 MFMAs (4 row-tiles x K=64, hi-only) for one 16-code tile, then ACT.
// Identical arithmetic in both sweeps -> bit-identical s~ values.
#define DOT_TILE(ti, B0, B1, ACT)                                       \
    {                                                                   \
        const int codeL = code0 + (ti) * 16 + (l & 15);                 \
        const float eev = ee_s[codeL];                                  \
        _Pragma("unroll") for (int rt = 0; rt < 4; rt++) {              \
            f32x4 acc = {0.f, 0.f, 0.f, 0.f};                           \
            MFMA_BF16(acc, ah[rt][0], B0);                              \
            MFMA_BF16(acc, ah[rt][1], B1);                              \
            _Pragma("unroll") for (int r = 0; r < 4; r++) {             \
                float sv = fmaf(-2.0f, acc[r], eev);                    \
                ACT(rt, r, sv, codeL);                                  \
            }                                                           \
        }                                                               \
    }

#define ACT_MIN(rt, r, sv, code) rm[rt][r] = fminf(rm[rt][r], sv);
#define ACT_COLLECT(rt, r, sv, code)                                    \
    if (sv <= thr_r[rt][r]) {                                           \
        int row_ = rt * 16 + ((l >> 4) << 2) + r;                       \
        int pos_ = atomicAdd(&cnt_s[row_], 1);                          \
        if (pos_ < CAP) cand_s[row_][pos_] = (unsigned short)(code);    \
    }

#define PRE_B(ti)                                                       \
    {                                                                   \
        const unsigned short* p_ =                                      \
            ebase + (size_t)((ti) * 16 + (l & 15)) * 64 + kg;           \
        pb0[(ti) % 3] = *(const short8v*)p_;                            \
        pb1[(ti) % 3] = *(const short8v*)(p_ + 32);                     \
    }

// --- kernel A2: MFMA filter + exact rescore + fused outputs ---
// Block: 256 threads (4 waves), 64 rows = one (b,h). Wave wv owns codes
// [wv*256, wv*256+256) for ALL 64 rows (4 row-tile A-frags, hi bf16 only).
// MFMA 16x16x32 bf16: A[m][k]: m=lane&15, k=(lane>>4)*8+i; B[k][n]:
// n=lane&15, same k; D[m][n]: n=lane&15, m=(lane>>4)*4+reg (m89-verified).
__global__ __launch_bounds__(256, 4) void kA2(
    const float* __restrict__ z, const float* __restrict__ emb,
    const float* __restrict__ ee, const unsigned short* __restrict__ eh_p,
    int* __restrict__ counts, float* __restrict__ out_idx,
    float* __restrict__ out_q, double* __restrict__ loss_sum) {
    __shared__ float zt[64][65];       // [w][d]
    __shared__ float ee_s[KCODES];     // exact ee bit-copy
    __shared__ float zz_s[64];
    __shared__ float wq_s[64];         // per-row window W_row
    __shared__ float rmw_s[4][64];     // per-wave per-row mins
    __shared__ float thr_s[64];        // final per-row threshold
    __shared__ int cnt_s[64];
    __shared__ unsigned short cand_s[64][CAP];
    __shared__ int idx_s[64];
    __shared__ double wred[4];

    const int tid = threadIdx.x;
    const int blk = blockIdx.x;        // 0..2047
    const int n0 = blk * 64;
    const int b = blk >> 6;
    const int h = blk & 63;

    // stage z tile with float4 (coalesced: 16 lanes x 16B = one d-row)
    const float* zb = z + (size_t)b * 262144 + (size_t)h * 64;
#pragma unroll
    for (int it = 0; it < 4; it++) {
        int idx = it * 256 + tid;
        int d = idx >> 4, w4 = (idx & 15) * 4;
        float4 v = *(const float4*)(zb + (size_t)d * 4096 + w4);
        zt[w4 + 0][d] = v.x;
        zt[w4 + 1][d] = v.y;
        zt[w4 + 2][d] = v.z;
        zt[w4 + 3][d] = v.w;
    }
    for (int i = tid; i < KCODES; i += 256) ee_s[i] = ee[i];
    __syncthreads();

    if (tid < 64) {
        const int w = tid;
        zz_s[w] = pairwise64_sq([&](int i) { return zt[w][i]; });
        float s = 0.0f;
#pragma unroll
        for (int i = 0; i < 64; i++) s += fabsf(zt[w][i]);
        wq_s[w] = fmaf(2e-5f, s, 1e-4f);  // hi-only bound, >=2.6x margin
        cnt_s[w] = 0;
    }
    __syncthreads();

    const int wv = tid >> 6;           // wave id -> code range
    const int l = tid & 63;            // lane
    const int kg = (l >> 4) * 8;       // k-slice base within 32-wide half
    const int code0 = wv * 256;

    // A fragments (hi bf16 only) for all 64 rows = 4 row-tiles
    short8v ah[4][2];
#pragma unroll
    for (int rt = 0; rt < 4; rt++) {
        const int arow = rt * 16 + (l & 15);
#pragma unroll
        for (int kt = 0; kt < 2; kt++) {
#pragma unroll
            for (int i = 0; i < 8; i++)
                ah[rt][kt][i] = (short)bf16_rne(zt[arow][kt * 32 + kg + i]);
        }
    }

    const unsigned short* ebase = eh_p + (size_t)code0 * 64;

    // ---- sweep 1: per-row approx min over this wave's 256 codes ----
    float rm[4][4];
#pragma unroll
    for (int rt = 0; rt < 4; rt++)
#pragma unroll
        for (int r = 0; r < 4; r++) rm[rt][r] = INFINITY;
    {
        short8v pb0[3], pb1[3];
        PRE_B(0)
        PRE_B(1)
#pragma unroll
        for (int ti = 0; ti < 16; ti++) {
            if (ti + 2 < 16) PRE_B(ti + 2)
            DOT_TILE(ti, pb0[ti % 3], pb1[ti % 3], ACT_MIN)
        }
    }
    // reduce min across the 16 lanes (codes) in each lane group
#pragma unroll
    for (int rt = 0; rt < 4; rt++)
#pragma unroll
        for (int r = 0; r < 4; r++) {
            float v = rm[rt][r];
            v = fminf(v, __shfl_xor(v, 1, 64));
            v = fminf(v, __shfl_xor(v, 2, 64));
            v = fminf(v, __shfl_xor(v, 4, 64));
            v = fminf(v, __shfl_xor(v, 8, 64));
            rm[rt][r] = v;
        }
    if ((l & 15) == 0) {
#pragma unroll
        for (int rt = 0; rt < 4; rt++)
#pragma unroll
            for (int r = 0; r < 4; r++)
                rmw_s[wv][rt * 16 + ((l >> 4) << 2) + r] = rm[rt][r];
    }
    __syncthreads();
    if (tid < 64) {
        float m01 = fminf(rmw_s[0][tid], rmw_s[1][tid]);
        float m23 = fminf(rmw_s[2][tid], rmw_s[3][tid]);
        thr_s[tid] = fminf(m01, m23) + wq_s[tid];
    }
    __syncthreads();

    // hoist thresholds for this lane's 16 (rt,r) rows into registers
    float thr_r[4][4];
#pragma unroll
    for (int rt = 0; rt < 4; rt++)
#pragma unroll
        for (int r = 0; r < 4; r++)
            thr_r[rt][r] = thr_s[rt * 16 + ((l >> 4) << 2) + r];

    // ---- sweep 2: identical arithmetic, collect window candidates ----
    {
        short8v pb0[3], pb1[3];
        PRE_B(0)
        PRE_B(1)
#pragma unroll
        for (int ti = 0; ti < 16; ti++) {
            if (ti + 2 < 16) PRE_B(ti + 2)
            DOT_TILE(ti, pb0[ti % 3], pb1[ti % 3], ACT_COLLECT)
        }
    }
    __syncthreads();

    // ---- exact rescore (reference-bit-exact chain), one thread per row ----
    if (tid < 64) {
        const int w = tid;
        const float zzv = zz_s[w];
        float bv = INFINITY;
        int bi = 0;
        const int nc = cnt_s[w];
        if (nc > CAP) {
            for (int k = 0; k < KCODES; k++) {
                const float4* er = (const float4*)(emb + (size_t)k * 64);
                float dot = 0.0f;
#pragma unroll
                for (int q = 0; q < 16; q++) {
                    float4 e4 = er[q];
                    dot = __builtin_fmaf(zt[w][4 * q + 0], e4.x, dot);
                    dot = __builtin_fmaf(zt[w][4 * q + 1], e4.y, dot);
                    dot = __builtin_fmaf(zt[w][4 * q + 2], e4.z, dot);
                    dot = __builtin_fmaf(zt[w][4 * q + 3], e4.w, dot);
                }
                float tt = zzv + ee_s[k];
                float dv = tt - 2.0f * dot;
                if (dv < bv || (dv == bv && k < bi)) { bv = dv; bi = k; }
            }
        } else {
            for (int j = 0; j < nc; j++) {
                const int k = cand_s[w][j];
                const float4* er = (const float4*)(emb + (size_t)k * 64);
                float dot = 0.0f;
#pragma unroll
                for (int q = 0; q < 16; q++) {
                    float4 e4 = er[q];
                    dot = __builtin_fmaf(zt[w][4 * q + 0], e4.x, dot);
                    dot = __builtin_fmaf(zt[w][4 * q + 1], e4.y, dot);
                    dot = __builtin_fmaf(zt[w][4 * q + 2], e4.z, dot);
                    dot = __builtin_fmaf(zt[w][4 * q + 3], e4.w, dot);
                }
                float tt = zzv + ee_s[k];
                float dv = tt - 2.0f * dot;
                if (dv < bv || (dv == bv && k < bi)) { bv = dv; bi = k; }
            }
        }
        idx_s[w] = bi;
        out_idx[n0 + w] = (float)bi;
        atomicAdd(&counts[bi], 1);
    }
    __syncthreads();

    // ---- fused output: quantized gather/store + fp64 loss ----
    float* qb = out_q + (size_t)b * 262144 + (size_t)h * 64;
    double dsum = 0.0;
    for (int i = tid; i < 4096; i += 256) {
        int c = i >> 6, w = i & 63;
        float q = emb[(size_t)idx_s[w] * 64 + c];
        float zv = zt[w][c];
        qb[(size_t)c * 4096 + w] = q;
        float df = q - zv;
        float s = df * df;
        dsum += (double)s;
    }
    for (int off = 32; off > 0; off >>= 1) dsum += __shfl_down(dsum, off, 64);
    if ((tid & 63) == 0) wred[tid >> 6] = dsum;
    __syncthreads();
    if (tid == 0) {
        double tot = (wred[0] + wred[1]) + (wred[2] + wred[3]);
        atomicAdd(loss_sum, tot);
    }
}

// --- kernel C: loss + perplexity scalars ---
__global__ __launch_bounds__(1024) void kC(const int* __restrict__ counts,
                                           const double* __restrict__ loss_sum,
                                           float* __restrict__ out_loss,
                                           float* __restrict__ out_perp) {
    __shared__ float wr[16];
    const int tid = threadIdx.x;
    float p = (float)counts[tid] * (1.0f / 131072.0f);
    float v = p + 1e-10f;
    float term = p * logf(v);
    float s = term;
    for (int off = 32; off > 0; off >>= 1) s += __shfl_down(s, off, 64);
    if ((tid & 63) == 0) wr[tid >> 6] = s;
    __syncthreads();
    if (tid == 0) {
        float tot = 0.0f;
#pragma unroll
        for (int j = 0; j < 16; j++) tot += wr[j];
        out_perp[0] = expf(-tot);
        double L = *loss_sum / 8388608.0;
        float Lf = (float)L;
        out_loss[0] = Lf + 0.25f * Lf;
    }
}

extern "C" void kernel_launch(void* const* d_in, const int* in_sizes, int n_in,
                              void* d_out, int out_size, void* d_ws, size_t ws_size,
                              hipStream_t stream) {
    const float* z = (const float*)d_in[0];
    const float* emb = (const float*)d_in[1];
    float* out = (float*)d_out;
    float* out_q = out;                    // 8388608
    float* out_loss = out + 8388608;       // 1
    float* out_perp = out + 8388609;       // 1
    float* out_idx = out + 8388610;        // 131072

    char* ws = (char*)d_ws;
    double* loss_sum = (double*)ws;                       // 8 B @ 0
    int* counts = (int*)(ws + 64);                        // 4 KB
    float* ee = (float*)(ws + 64 + 4096);                 // 4 KB
    unsigned short* eh_p = (unsigned short*)(ws + 64 + 8192);  // 128 KB

    hipMemsetAsync(d_ws, 0, 64 + 4096, stream);
    kE<<<4, 256, 0, stream>>>(emb, ee, eh_p);
    kA2<<<2048, 256, 0, stream>>>(z, emb, ee, eh_p, counts, out_idx, out_q,
                                  loss_sum);
    kC<<<1, 1024, 0, stream>>>(counts, loss_sum, out_loss, out_perp);
}